// Round 5
// baseline (200.496 us; speedup 1.0000x reference)
//
#include <hip/hip_runtime.h>
#include <hip/hip_bf16.h>

#define N_NODES 16384
#define K_NBR 16
#define HOPS 4
#define IN_DIM 256
#define RAW_DIM 128
#define OUT_DIM 64
#define PHI_DIM 16
#define N_KERN 4
#define E_EDGES (N_NODES * K_NBR)

typedef __hip_bfloat16 bf16;
typedef __attribute__((ext_vector_type(8))) short short8;
typedef __attribute__((ext_vector_type(4))) float f32x4;
typedef __attribute__((ext_vector_type(2))) float f32x2;
typedef __attribute__((ext_vector_type(4))) unsigned int uint4v;

__device__ __forceinline__ float toF(float x) { return x; }
__device__ __forceinline__ float toF(bf16 x) { return __bfloat162float(x); }
__device__ __forceinline__ short f2bfbits(float f)
{
    bf16 b = __float2bfloat16(f);
    short s; __builtin_memcpy(&s, &b, 2); return s;
}

// LDS XOR swizzle (64-short rows): flips short-index bits 3..5 within a row.
// WRITE side is global_load_lds (linear LDS dest) with the same involution
// applied to the global SOURCE chunk index (both-sides-or-neither).
#define SWZ(row, colShort) ((colShort) ^ (((row) & 7) << 3))
// 32-short-row variant (hk BK=32): chunk ^= (row>>1)&3. With the row*64B
// stride, bank = 16*(row&1) + 4*(chunk^((row>>1)&3)) -> 2-way max (free).
#define SWZ32(row, colShort) ((colShort) ^ ((((row) >> 1) & 3) << 3))

// async 16B global->LDS (linear dest = wave base + lane*16)
__device__ __forceinline__ void gld_lds16(const bf16* g, short* l)
{
    __builtin_amdgcn_global_load_lds(
        (const __attribute__((address_space(1))) unsigned int*)g,
        (__attribute__((address_space(3))) unsigned int*)l, 16, 0, 0);
}

// ds_swizzle xor-reduce step (BitMode: offset = (xor<<10)|0x1F); 1 DS op,
// no per-shuffle VALU address math (vs __shfl_xor's bpermute path).
template <int IMM>
__device__ __forceinline__ float swzx(float v)
{
    return __builtin_bit_cast(float,
        __builtin_amdgcn_ds_swizzle(__builtin_bit_cast(int, v), IMM));
}
#define XOR1  0x041F
#define XOR2  0x081F
#define XOR4  0x101F
#define XOR8  0x201F
#define XOR16 0x401F

// packed f32 FMA, acc = broadcast(w.word0 or word1) * x + acc (VOP3P op_sel)
__device__ __forceinline__ void pkfma_w0(f32x2& acc, f32x2 w, f32x2 x)
{
    asm("v_pk_fma_f32 %0, %1, %2, %0 op_sel:[0,0,0] op_sel_hi:[0,1,1]"
        : "+v"(acc) : "v"(w), "v"(x));
}
__device__ __forceinline__ void pkfma_w1(f32x2& acc, f32x2 w, f32x2 x)
{
    asm("v_pk_fma_f32 %0, %1, %2, %0 op_sel:[1,0,0] op_sel_hi:[1,1,1]"
        : "+v"(acc) : "v"(w), "v"(x));
}

// --------------------------- f32 workspace layout --------------------------
#define CV_WPHI 0
#define CV_W1   (CV_WPHI + HOPS * RAW_DIM * (PHI_DIM - 1))
#define CV_B1   (CV_W1 + HOPS * RAW_DIM * IN_DIM)
#define CV_W2   (CV_B1 + HOPS * IN_DIM)
#define CV_B2   (CV_W2 + HOPS * IN_DIM * PHI_DIM * N_KERN)
#define CV_TPHI (CV_B2 + HOPS * PHI_DIM * N_KERN)
#define CV_W    (CV_TPHI + HOPS * N_KERN * PHI_DIM)
#define CV_BIAS (CV_W + HOPS * IN_DIM * OUT_DIM * N_KERN)
#define CV_Z    (CV_BIAS + HOPS * OUT_DIM)
#define CV_END  (CV_Z + OUT_DIM)

// transposed bf16 weight region sizes
#define WT_N  (HOPS * 256 * 256)
#define W1T_N (HOPS * 256 * 128)
#define W2T_N (HOPS * 64 * 256)
#define WPT_N (HOPS * 16 * 128)
#define CVT_TOTAL (WT_N + W1T_N + W2T_N + WPT_N)

// cvt_all block ranges
#define NB_CV ((CV_END + 255) / 256)
#define NB_WT (CVT_TOTAL / 256)                      // exact
#define NB_H  (N_NODES * 256 / 8 / 256)              // h vec8 units
#define NB_E  (HOPS * N_NODES * 128 / 8 / 256)       // e vec8 units
#define NB_ALL (NB_CV + NB_WT + NB_H + NB_E + 1)

// gemm_all: A = hk gemm (1024 blocks), B = hid_delta+phi (1024 blocks).
// Type alternates every 8 blocks so the XCD round-robin (blockIdx%8) makes
// co-resident blocks on a CU be of DIFFERENT types (hk MFMA fills hid stalls).
#define GA_TOTAL 2048

__device__ __forceinline__ float loadDyn(const void* p, int i, bool isbf)
{
    return isbf ? toF(((const bf16*)p)[i]) : ((const float*)p)[i];
}

// 8-wide dyn -> bf16 conversion helper
__device__ __forceinline__ void cvt8(bf16* dst, const void* src, size_t base, bool isbf)
{
    short8 v;
    if (isbf) {
        v = *(const short8*)((const bf16*)src + base);
    } else {
        const float* sp = (const float*)src + base;
        f32x4 f0 = *(const f32x4*)sp;
        f32x4 f1 = *(const f32x4*)(sp + 4);
#pragma unroll
        for (int j = 0; j < 4; j++) { v[j] = f2bfbits(f0[j]); v[4 + j] = f2bfbits(f1[j]); }
    }
    *(short8*)(dst + base) = v;
}

// ---------------------------------------------------------------------------
// cvt_all: (a) small weights -> f32 CV, (b) transposed bf16 weights,
// (c) h -> bf16, (d) e -> bf16 (vec8), (e) tn + l_sep + FLAG/ACC (last block).
// Each block SELF-DETECTS dtype from h's first 256 shorts.
// ---------------------------------------------------------------------------
__global__ __launch_bounds__(256) void cvt_all(
    const void* h, const void* e,
    const void* wphi, const void* w1, const void* b1, const void* w2,
    const void* b2, const void* tphi, const void* W, const void* bias,
    const void* z, float* __restrict__ CV,
    bf16* __restrict__ wt, bf16* __restrict__ w1t, bf16* __restrict__ w2t,
    bf16* __restrict__ wpt, bf16* __restrict__ h_bf, bf16* __restrict__ e_bf,
    float* __restrict__ tn_out, float* __restrict__ acc, int* __restrict__ flagOut)
{
    __shared__ float s_det[4];
    int tid = threadIdx.x;
    // ---- self-detect ----
    {
        unsigned short pv = ((const unsigned short*)h)[tid];
        unsigned int bits = ((unsigned int)pv) << 16;
        float v; __builtin_memcpy(&v, &bits, 4);
        v = fabsf(v);
        if (!(v == v) || v > 1e30f) v = 1e30f;
#pragma unroll
        for (int off = 32; off > 0; off >>= 1) v = fmaxf(v, __shfl_xor(v, off));
        if ((tid & 63) == 0) s_det[tid >> 6] = v;
    }
    __syncthreads();
    bool isbf = fmaxf(fmaxf(s_det[0], s_det[1]), fmaxf(s_det[2], s_det[3])) < 1e4f;

    int b = blockIdx.x;
    if (b == NB_ALL - 1) {
        // ---- tn = row-normalized tilde_phi (no eps) + l_sep; writes ACC/FLAG ----
        __shared__ float s_v[256], s_tn[256], s_red[256], s_hop[4];
        int hop = tid >> 6, t64 = tid & 63;
        int row = t64 >> 4, p = t64 & 15;
        float v = loadDyn(tphi, hop * 64 + t64, isbf);
        s_v[tid] = v;
        __syncthreads();
        float ss = 0.f;
        for (int q = 0; q < 16; q++) { float x = s_v[hop * 64 + row * 16 + q]; ss += x * x; }
        float tnv = v / sqrtf(ss);
        tn_out[hop * 64 + t64] = tnv;
        s_tn[tid] = tnv;
        __syncthreads();
        float s = 0.f;
        for (int j = 0; j < 4; j++) {
            float d = tnv - s_tn[hop * 64 + j * 16 + p];
            s += d * d;
        }
        s_red[tid] = s;
        __syncthreads();
        if (t64 == 0) {
            float tot = 0.f;
            for (int i = 0; i < 64; i++) tot += s_red[hop * 64 + i];
            s_hop[hop] = tot;
        }
        __syncthreads();
        if (tid == 0) {
            // l_sep = mean over hops of (tot_hop / nk) = sum * (1/4) * (1/4)
            acc[0] = (s_hop[0] + s_hop[1] + s_hop[2] + s_hop[3]) * 0.0625f;
            acc[1] = 0.f;                        // l_focus accumulator
            *flagOut = isbf ? 1 : 0;
        }
        return;
    }
    if (b < NB_CV) {
        int idx = b * 256 + tid;
        if (idx >= CV_END) return;
        float v;
        if      (idx < CV_W1)   v = loadDyn(wphi, idx - CV_WPHI, isbf);
        else if (idx < CV_B1)   v = loadDyn(w1,   idx - CV_W1,   isbf);
        else if (idx < CV_W2)   v = loadDyn(b1,   idx - CV_B1,   isbf);
        else if (idx < CV_B2)   v = loadDyn(w2,   idx - CV_W2,   isbf);
        else if (idx < CV_TPHI) v = loadDyn(b2,   idx - CV_B2,   isbf);
        else if (idx < CV_W)    v = loadDyn(tphi, idx - CV_TPHI, isbf);
        else if (idx < CV_BIAS) v = loadDyn(W,    idx - CV_W,    isbf);
        else if (idx < CV_Z)    v = loadDyn(bias, idx - CV_BIAS, isbf);
        else                    v = loadDyn(z,    idx - CV_Z,    isbf);
        CV[idx] = v;
        return;
    }
    b -= NB_CV;
    if (b < NB_WT) {
        int idx = b * 256 + tid;
        if (idx < WT_N) {                      // 256N x 256K per hop
            int o = idx, hop = o >> 16, rem = o & 65535, n = rem >> 8, k = rem & 255;
            wt[o] = __float2bfloat16(loadDyn(W, hop * 65536 + k * 256 + n, isbf));
        } else if (idx < WT_N + W1T_N) {       // 256N x 128K per hop
            int o = idx - WT_N, hop = o >> 15, rem = o & 32767, n = rem >> 7, k = rem & 127;
            w1t[o] = __float2bfloat16(loadDyn(w1, hop * 32768 + k * 256 + n, isbf));
        } else if (idx < WT_N + W1T_N + W2T_N) { // 64N x 256K per hop
            int o = idx - WT_N - W1T_N, hop = o >> 14, rem = o & 16383, n = rem >> 8, k = rem & 255;
            w2t[o] = __float2bfloat16(loadDyn(w2, hop * 16384 + k * 64 + n, isbf));
        } else {                               // 16N x 128K per hop (row 15 zero)
            int o = idx - WT_N - W1T_N - W2T_N, hop = o >> 11, rem = o & 2047, n = rem >> 7, k = rem & 127;
            float v = (n < 15) ? loadDyn(wphi, hop * 1920 + k * 15 + n, isbf) : 0.f;
            wpt[o] = __float2bfloat16(v);
        }
        return;
    }
    b -= NB_WT;
    if (b < NB_H) {
        size_t base = ((size_t)b * 256 + tid) * 8;
        cvt8(h_bf, h, base, isbf);
        return;
    }
    b -= NB_H;
    {
        size_t base = ((size_t)b * 256 + tid) * 8;
        cvt8(e_bf, e, base, isbf);
    }
}

// ---------------------------------------------------------------------------
// hk GEMM: C = h @ W, 128x128 tile, K=256, BK=32, 2-phase double-buffered.
// LDS: buf b at smem + b*16KB: As[128][32] + Bs[128][32] (linear, source-
// swizzled SWZ32 via gld_lds). One barrier per K-step; stage(t+1) issued
// before compute(t). Total 32 KB -> fits the 45056 B kernel high-water.
// Output fp8-e4m3 staged through LDS (aliases buf0 after final barrier).
// ---------------------------------------------------------------------------
__device__ __forceinline__ void gemm_hk_dev(
    char* smem, const bf16* __restrict__ A, const bf16* __restrict__ Bt,
    unsigned char* __restrict__ Cg, int colBase, int rowBase)
{
    short* base = (short*)smem;
    int tid = threadIdx.x;
    int w = tid >> 6, lane = tid & 63;
    int wr = w >> 1, wc = w & 1;
    int l16 = lane & 15, quad = lane >> 4;
    f32x4 acc[4][4] = {};

#define HK_STAGE(bufb, k0v)                                                          \
    {                                                                                \
        short* As_ = base + (bufb) * 8192;                                           \
        short* Bs_ = As_ + 4096;                                                     \
        for (int id = tid; id < 128 * 4; id += 256) {                                \
            int row = id >> 2, j = id & 3;                                           \
            gld_lds16(A + (size_t)(rowBase + row) * 256 + (k0v) +                    \
                          ((j ^ ((row >> 1) & 3)) * 8),                              \
                      As_ + id * 8);                                                 \
        }                                                                            \
        for (int id = tid; id < 128 * 4; id += 256) {                                \
            int row = id >> 2, j = id & 3;                                           \
            gld_lds16(Bt + (size_t)(colBase + row) * 256 + (k0v) +                   \
                          ((j ^ ((row >> 1) & 3)) * 8),                              \
                      Bs_ + id * 8);                                                 \
        }                                                                            \
    }

    HK_STAGE(0, 0)
    __syncthreads();                       // prologue drain
    for (int t = 0; t < 8; ++t) {
        if (t < 7) HK_STAGE((t + 1) & 1, (t + 1) * 32)   // prefetch next K-slab
        short* As = base + (t & 1) * 8192;
        short* Bs = As + 4096;
        short8 aF[4], bF[4];
#pragma unroll
        for (int mi = 0; mi < 4; mi++) {
            int row = wr * 64 + mi * 16 + l16;
            aF[mi] = *(const short8*)&As[row * 32 + SWZ32(row, quad * 8)];
        }
#pragma unroll
        for (int ni = 0; ni < 4; ni++) {
            int row = wc * 64 + ni * 16 + l16;
            bF[ni] = *(const short8*)&Bs[row * 32 + SWZ32(row, quad * 8)];
        }
#pragma unroll
        for (int mi = 0; mi < 4; mi++)
#pragma unroll
            for (int ni = 0; ni < 4; ni++)
                acc[mi][ni] = __builtin_amdgcn_mfma_f32_16x16x32_bf16(
                    aF[mi], bF[ni], acc[mi][ni], 0, 0, 0);
        __syncthreads();                   // drains prefetch + guards buffer swap
    }
#undef HK_STAGE

    // fp8 epilogue staged in smem [128][128] bytes (buf region, dead now)
    unsigned char* Cs = (unsigned char*)smem;
#pragma unroll
    for (int mi = 0; mi < 4; mi++)
#pragma unroll
        for (int ni = 0; ni < 4; ni++) {
            int cl = wc * 64 + ni * 16 + l16;
#pragma unroll
            for (int r = 0; r < 4; r++) {
                int rl = wr * 64 + mi * 16 + quad * 4 + r;
                float v = acc[mi][ni][r];
                int pk = __builtin_amdgcn_cvt_pk_fp8_f32(v, v, 0, false);
                Cs[rl * 128 + cl] = (unsigned char)(pk & 0xFF);
            }
        }
    __syncthreads();
    for (int c = tid; c < 128 * 8; c += 256) {
        int r = c >> 3, off = (c & 7) * 16;
        *(uint4v*)(Cg + ((size_t)(rowBase + r) * 256 + colBase) + off) =
            *(const uint4v*)(Cs + (size_t)r * 128 + off);
    }
}

// ---------------------------------------------------------------------------
// hid_delta+phi device body: hid = relu(e@w1+b1) (LDS-only) -> delta =
// hid@w2+b2 (+tn, l_focus); phi = e@Wphi folded into phase 1 (wave 0) since
// the e-tile is already staged. 64-row tile.
// LDS plan (shorts; 45056 B total, heavy aliasing):
//   phase 1: As[64][64] @0 (8K) | Bs[256][64] @4096 (32K) | Wpa[16][128] @20480 (4K)
//   phase 2: Hs[64][256] @0 (32K, aliases As+Bs) | B2s[64][64] @16384 (8K)
//   epilogue: Ds[64][64] f32 @0 (16K); s_w @byte 40944 (B2s tail, dead)
// ---------------------------------------------------------------------------
__device__ __forceinline__ void hid_delta_dev(
    char* smem,
    const bf16* __restrict__ A, const bf16* __restrict__ B1,
    const bf16* __restrict__ B2, const bf16* __restrict__ WP,
    const float* __restrict__ b1, const float* __restrict__ b2,
    const float* __restrict__ tn, float* __restrict__ Dg,
    float* __restrict__ phiG, float* __restrict__ lfocus, int rowBase)
{
    short* As  = (short*)smem;           // [64][64] phase 1
    short* Bs  = As + 64 * 64;           // [256][64] phase 1
    short* Wpa = As + 20480;             // [16][128] full-K Wphi^T
    short* Hs  = (short*)smem;           // [64][256] phase 2 (aliases As/Bs)
    short* B2s = Hs + 64 * 256;          // [64][64] phase 2 quarter buffer
    float* Ds  = (float*)smem;           // [64][64] f32 epilogue
    float* s_w = (float*)(smem + 40944); // tail of B2s

    int tid = threadIdx.x;
    int w = tid >> 6, lane = tid & 63;
    int l16 = lane & 15, quad = lane >> 4;

    // ---- phase 1: hid = relu(e @ w1 + b1) -> Hs ; phi (wave 0) ----
    {
        f32x4 acc[4][4] = {};
        f32x4 accp[4] = {};
        for (int k0 = 0; k0 < 128; k0 += 64) {
            for (int id = tid; id < 64 * 8; id += 256) {
                int row = id >> 3, j = id & 7;
                gld_lds16(A + (size_t)(rowBase + row) * 128 + k0 + ((j ^ (row & 7)) * 8),
                          As + id * 8);
            }
            for (int id = tid; id < 256 * 8; id += 256) {
                int row = id >> 3, j = id & 7;
                gld_lds16(B1 + (size_t)row * 128 + k0 + ((j ^ (row & 7)) * 8),
                          Bs + id * 8);
            }
            if (k0 == 0) {                 // Wphi^T: 16 rows x 16 chunks, full K
                int row = tid >> 4, j = tid & 15;
                gld_lds16(WP + (size_t)row * 128 + ((j ^ (row & 7)) * 8),
                          Wpa + tid * 8);
            }
            __syncthreads();
#pragma unroll
            for (int kc = 0; kc < 64; kc += 32) {
                short8 aF[4], bF[4];
#pragma unroll
                for (int mi = 0; mi < 4; mi++) {
                    int row = mi * 16 + l16;
                    aF[mi] = *(const short8*)&As[row * 64 + SWZ(row, kc + quad * 8)];
                }
#pragma unroll
                for (int ni = 0; ni < 4; ni++) {
                    int row = w * 64 + ni * 16 + l16;
                    bF[ni] = *(const short8*)&Bs[row * 64 + SWZ(row, kc + quad * 8)];
                }
#pragma unroll
                for (int mi = 0; mi < 4; mi++)
#pragma unroll
                    for (int ni = 0; ni < 4; ni++)
                        acc[mi][ni] = __builtin_amdgcn_mfma_f32_16x16x32_bf16(
                            aF[mi], bF[ni], acc[mi][ni], 0, 0, 0);
                if (w == 0) {
                    short8 bFp = *(const short8*)&Wpa[l16 * 128 + SWZ(l16, k0 + kc + quad * 8)];
#pragma unroll
                    for (int mi = 0; mi < 4; mi++)
                        accp[mi] = __builtin_amdgcn_mfma_f32_16x16x32_bf16(
                            aF[mi], bFp, accp[mi], 0, 0, 0);
                }
            }
            __syncthreads();
        }
        // epilogue -> Hs (As/Bs dead); stage B2 quarter 0; write phi (wave 0)
#pragma unroll
        for (int mi = 0; mi < 4; mi++) {
#pragma unroll
            for (int ni = 0; ni < 4; ni++) {
                int col = w * 64 + ni * 16 + l16;
                float bv = b1[col];
#pragma unroll
                for (int r = 0; r < 4; r++) {
                    int row = mi * 16 + quad * 4 + r;
                    float v = fmaxf(acc[mi][ni][r] + bv, 0.f);
                    Hs[row * 256 + SWZ(row, col)] = f2bfbits(v);
                }
            }
        }
        for (int id = tid; id < 64 * 8; id += 256) {     // B2 quarter 0
            int row = id >> 3, j = id & 7;
            gld_lds16(B2 + (size_t)row * 256 + ((j ^ (row & 7)) * 8),
                      B2s + id * 8);
        }
        if (w == 0) {
#pragma unroll
            for (int mi = 0; mi < 4; mi++)
#pragma unroll
                for (int r = 0; r < 4; r++)
                    phiG[(size_t)(rowBase + mi * 16 + quad * 4 + r) * 16 + l16] =
                        accp[mi][r];
        }
    }

    // ---- phase 2: delta = Hs @ w2 + b2 (w2 staged in K=64 quarters) ----
    {
        f32x4 acc2[4] = {};
        for (int q = 0; q < 4; q++) {
            __syncthreads();   // q=0: Hs+B2s0 writes done; q>0: prev reads done
#pragma unroll
            for (int kcq = 0; kcq < 64; kcq += 32) {
                int arow = w * 16 + l16;
                short8 aF = *(const short8*)&Hs[arow * 256 + SWZ(arow, q * 64 + kcq + quad * 8)];
                short8 bF[4];
#pragma unroll
                for (int ni = 0; ni < 4; ni++) {
                    int row = ni * 16 + l16;
                    bF[ni] = *(const short8*)&B2s[row * 64 + SWZ(row, kcq + quad * 8)];
                }
#pragma unroll
                for (int ni = 0; ni < 4; ni++)
                    acc2[ni] = __builtin_amdgcn_mfma_f32_16x16x32_bf16(aF, bF[ni], acc2[ni], 0, 0, 0);
            }
            if (q < 3) {
                __syncthreads();                         // all reads of quarter q done
                for (int id = tid; id < 64 * 8; id += 256) {
                    int row = id >> 3, j = id & 7;
                    gld_lds16(B2 + (size_t)row * 256 + (q + 1) * 64 + ((j ^ (row & 7)) * 8),
                              B2s + id * 8);
                }
            }
        }
        __syncthreads();   // all MFMA reads done before Ds/s_w overwrite LDS
        float sq = 0.f;
#pragma unroll
        for (int ni = 0; ni < 4; ni++) {
            int col = ni * 16 + l16;
            float bv = b2[col], tv = tn[col];
#pragma unroll
            for (int r = 0; r < 4; r++) {
                int row = w * 16 + quad * 4 + r;
                float v = acc2[ni][r] + bv;
                sq += v * v;
                Ds[row * 64 + col] = v + tv;
            }
        }
#pragma unroll
        for (int off = 32; off > 0; off >>= 1) sq += __shfl_xor(sq, off);
        if (lane == 0) s_w[w] = sq;
        __syncthreads();
        for (int c = tid; c < 64 * 16; c += 256) {       // 16 x 16B chunks/row
            int r = c >> 4, off = (c & 15) * 4;
            *(uint4v*)(Dg + (size_t)(rowBase + r) * 64 + off) =
                *(const uint4v*)(Ds + (size_t)r * 64 + off);
        }
        if (tid == 0) atomicAdd(lfocus, s_w[0] + s_w[1] + s_w[2] + s_w[3]);
    }
}

// ---------------------------------------------------------------------------
// gemm_all: hk gemm (A, 1024 blocks, BK=32 dbuf) + hid_delta+phi (B, 1024).
// Type = (b>>3)&1 so the XCD round-robin co-schedules A with B on each CU.
// smem = 45056 B (hid high-water) -> 3 blocks/CU.
// ---------------------------------------------------------------------------
__global__ __launch_bounds__(256) void gemm_all(
    const bf16* __restrict__ h_bf, const bf16* __restrict__ e_bf,
    const bf16* __restrict__ WT, const bf16* __restrict__ WPT,
    const bf16* __restrict__ W1T, const bf16* __restrict__ W2T,
    const float* __restrict__ b1All, const float* __restrict__ b2All,
    const float* __restrict__ tnAll, unsigned char* __restrict__ hk_f8,
    float* __restrict__ phi, float* __restrict__ DELTA, float* __restrict__ lfocus)
{
    __shared__ __align__(16) char smem[45056];
    int b = blockIdx.x;
    bool isA = ((b >> 3) & 1) == 0;
    int a = ((b >> 4) << 3) | (b & 7);    // index within type, balanced
    int hop = a >> 8;
    if (isA) {
        int r = a & 255, part = r >> 7, row = r & 127;
        gemm_hk_dev(smem, h_bf, WT + (size_t)hop * 65536,
                    hk_f8 + (size_t)hop * N_NODES * 256, part * 128, row * 128);
    } else {
        int tile = a & 255;
        hid_delta_dev(smem,
            e_bf + (size_t)hop * N_NODES * 128,
            W1T + (size_t)hop * 32768, W2T + (size_t)hop * 16384,
            WPT + (size_t)hop * 2048,
            b1All + hop * 256, b2All + hop * 64, tnAll + hop * 64,
            DELTA + (size_t)hop * N_NODES * 64,
            phi + (size_t)hop * N_NODES * 16, lfocus, tile * 64);
    }
}

// ---------------------------------------------------------------------------
// edge_agg2: wave-synchronous, 4 nodes (one hop) per 256-thread block.
// hop = blockIdx.x & 3 (XCD affinity). VALU-diet version: ds_swizzle
// xor-reductions (no bpermute addr math), v_pk_fma_f32 with op_sel weight
// broadcast in the gather loop, v_rsq/v_rcp instead of precise div/sqrt
// (1/max(sqrt(x),1e-8) == min(rsq(x),1e8) by monotonicity).
// ---------------------------------------------------------------------------
__global__ __launch_bounds__(256) void edge_agg2(
    const unsigned char* __restrict__ hk, const float* __restrict__ phi,
    const float* __restrict__ dik, const int* __restrict__ src,
    const float* __restrict__ biasAll, float* __restrict__ outs)
{
    int b = blockIdx.x;
    int hop = b & 3;                 // XCD affinity: hop h -> XCDs {h, h+4}
    int wave = threadIdx.x >> 6, lane = threadIdx.x & 63;
    int node = (b >> 2) * 4 + wave;
    const unsigned char* hk_l = hk + (size_t)hop * N_NODES * 256;
    const float* phi_l  = phi + (size_t)hop * N_NODES * 16;
    const float* dik_l  = dik + (size_t)hop * N_NODES * 64;
    const int*   src_n  = src + (size_t)hop * E_EDGES + (size_t)node * 16;
    const float* bias_l = biasAll + hop * 64;
    float*       outs_n = outs + ((size_t)hop * N_NODES + node) * 64;

    __shared__ __align__(16) float s_dik[4][64];
    __shared__ __align__(16) float s_attT[4][4][24];  // [wave][k][edge]
    __shared__ int   s_src[4][16];

    s_dik[wave][lane] = dik_l[(size_t)node * 64 + lane];
    if (lane < 16) s_src[wave][lane] = src_n[lane];

    // ---- stage 1: dist + logits (4 lanes per edge; lane = 4e + q) ----
    int e = lane >> 2, q = lane & 3;
    int sN = s_src[wave][e];
    f32x4 ps = *(const f32x4*)(phi_l + (size_t)sN * 16 + q * 4);
    f32x4 pd = *(const f32x4*)(phi_l + (size_t)node * 16 + q * 4);
    float d0 = ps[0] - pd[0], d1 = ps[1] - pd[1];
    float d2 = ps[2] - pd[2], d3 = ps[3] - pd[3];
    bool q3 = (q == 3);            // p15 = flag col (phi col15 == 0)
    float ssp = d0 * d0 + d1 * d1 + d2 * d2 + (q3 ? 0.f : d3 * d3);
    ssp += swzx<XOR1>(ssp); ssp += swzx<XOR2>(ssp);
    float last = (ssp == 0.f) ? 1.f : 0.f;   // all dist==0 <=> ssp==0 (see header)
    if (q3) d3 = last;
    float inv = fminf(__builtin_amdgcn_rsqf(ssp + last * last), 1e8f);
#pragma unroll
    for (int k = 0; k < 4; k++) {
        f32x4 dkv = *(const f32x4*)&s_dik[wave][k * 16 + q * 4];
        float pk = d0 * dkv[0] + d1 * dkv[1] + d2 * dkv[2] + d3 * dkv[3];
        pk += swzx<XOR1>(pk); pk += swzx<XOR2>(pk);
        if (q == k) s_attT[wave][k][e] = pk * inv;
    }

    // ---- stage 2: softmax over 16 edges per k (lane = 4e + k) ----
    int k2 = lane & 3;
    float lgv = s_attT[wave][k2][e];
    float mx = lgv;
    mx = fmaxf(mx, swzx<XOR4>(mx));
    mx = fmaxf(mx, swzx<XOR8>(mx));
    mx = fmaxf(mx, swzx<XOR16>(mx));
    mx = fmaxf(mx, __shfl_xor(mx, 32));
    float ex = __expf(lgv - mx);
    float den = ex;
    den += swzx<XOR4>(den);
    den += swzx<XOR8>(den);
    den += swzx<XOR16>(den);
    den += __shfl_xor(den, 32);
    s_attT[wave][k2][e] = ex * __builtin_amdgcn_rcpf(den);

    // ---- stage 3: aggregation (lane = kk*16 + dim-group; 4 dims/lane) ----
    int kk = lane >> 4, dsub = (lane & 15) * 4;
    f32x2 att2[8];
#pragma unroll
    for (int g = 0; g < 8; g++) att2[g] = *(const f32x2*)&s_attT[wave][kk][g * 2];
    f32x2 a01 = {0.f, 0.f}, a23 = {0.f, 0.f};
#pragma unroll
    for (int ep = 0; ep < 8; ep++) {
        int sm0 = __builtin_amdgcn_readfirstlane(s_src[wave][2 * ep]);
        int sm1 = __builtin_amdgcn_readfirstlane(s_src[wave][2 * ep + 1]);
        unsigned int u0 = *(const unsigned int*)(hk_l + (size_t)sm0 * 256 + lane * 4);
        unsigned int u1 = *(const unsigned int*)(hk_l + (size_t)sm1 * 256 + lane * 4);
        f32x2 w = att2[ep];
        pkfma_w0(a01, w, __builtin_amdgcn_cvt_pk_f32_fp8((int)u0, false));
        pkfma_w0(a23, w, __builtin_amdgcn_cvt_pk_f32_fp8((int)u0, true));
        pkfma_w1(a01, w, __builtin_amdgcn_cvt_pk_f32_fp8((int)u1, false));
        pkfma_w1(a23, w, __builtin_amdgcn_cvt_pk_f32_fp8((int)u1, true));
    }
    float a0 = a01[0], a1 = a01[1], a2 = a23[0], a3 = a23[1];
    a0 += swzx<XOR16>(a0); a0 += __shfl_xor(a0, 32);
    a1 += swzx<XOR16>(a1); a1 += __shfl_xor(a1, 32);
    a2 += swzx<XOR16>(a2); a2 += __shfl_xor(a2, 32);
    a3 += swzx<XOR16>(a3); a3 += __shfl_xor(a3, 32);
    f32x4 bv = *(const f32x4*)(bias_l + dsub);
    float o0 = a0 + bv[0];
    float o1 = a1 + bv[1];
    float o2 = a2 + bv[2];
    float o3 = a3 + bv[3];
    float ssq = o0 * o0 + o1 * o1 + o2 * o2 + o3 * o3;
    ssq += swzx<XOR1>(ssq);
    ssq += swzx<XOR2>(ssq);
    ssq += swzx<XOR4>(ssq);
    ssq += swzx<XOR8>(ssq);
    float inv2 = fminf(__builtin_amdgcn_rsqf(ssq), 1e8f);
    if (kk == 0) {
        f32x4 st;
        st[0] = o0 * inv2; st[1] = o1 * inv2; st[2] = o2 * inv2; st[3] = o3 * inv2;
        *(f32x4*)(outs_n + dsub) = st;
    }
}

// Hop fusion + output store (dtype by flag) + scalar outputs (block 0).
__global__ __launch_bounds__(256) void fuse_kernel(
    const float* __restrict__ outs, const float* __restrict__ z,
    void* __restrict__ out, const int* __restrict__ flag,
    const float* __restrict__ acc)
{
    int tid = threadIdx.x;
    int node = blockIdx.x * 4 + (tid >> 6);
    int dd = tid & 63;
    float zv = z[dd];
    float o[4], sc[4];
#pragma unroll
    for (int h = 0; h < 4; h++) {
        o[h] = outs[((size_t)h * N_NODES + node) * 64 + dd];
        float v = o[h] * zv;
#pragma unroll
        for (int off = 32; off > 0; off >>= 1) v += __shfl_xor(v, off);
        sc[h] = v;
    }
    float mx = fmaxf(fmaxf(sc[0], sc[1]), fmaxf(sc[2], sc[3]));
    float e0 = __expf(sc[0] - mx), e1 = __expf(sc[1] - mx);
    float e2 = __expf(sc[2] - mx), e3 = __expf(sc[3] - mx);
    float den = e0 + e1 + e2 + e3;
    float t = (e0 * o[0] + e1 * o[1] + e2 * o[2] + e3 * o[3]) * __builtin_amdgcn_rcpf(den);
    size_t oi = (size_t)node * 64 + dd;
    bool isbf = (*flag != 0);
    if (isbf) ((bf16*)out)[oi] = __float2bfloat16(t);
    else      ((float*)out)[oi] = t;
    if (blockIdx.x == 0 && tid == 0) {
        float a = acc[0];                                 // l_sep (already scaled)
        float b = acc[1] / ((float)N_NODES * 4.f * 4.f);  // l_focus mean
        size_t base = (size_t)N_NODES * 64;
        if (isbf) {
            ((bf16*)out)[base]     = __float2bfloat16(a);
            ((bf16*)out)[base + 1] = __float2bfloat16(b);
        } else {
            ((float*)out)[base]     = a;
            ((float*)out)[base + 1] = b;
        }
    }
}

extern "C" void kernel_launch(void* const* d_in, const int* in_sizes, int n_in,
                              void* d_out, int out_size, void* d_ws, size_t ws_size,
                              hipStream_t stream)
{
    const void* h    = d_in[0];
    const void* e    = d_in[1];
    const int*  src  = (const int*)d_in[2];
    const void* Wphi = d_in[4];
    const void* w1   = d_in[5];
    const void* b1   = d_in[6];
    const void* w2   = d_in[7];
    const void* b2   = d_in[8];
    const void* tphi = d_in[9];
    const void* W    = d_in[10];
    const void* bias = d_in[11];
    const void* z    = d_in[12];

    float* ws    = (float*)d_ws;
    float* CV    = ws;                                  // CV_END
    float* OUTS  = CV + CV_END;                         // 4*16384*64
    float* PHI   = OUTS + (size_t)4 * N_NODES * 64;     // 4*16384*16
    float* DELTA = PHI + (size_t)4 * N_NODES * 16;      // 4*16384*64
    float* TN    = DELTA + (size_t)4 * N_NODES * 64;    // 4*64
    float* ACC   = TN + 256;                            // 2 (+pad)
    int*   FLAG  = (int*)(ACC + 2);
    bf16*  H_BF  = (bf16*)(ACC + 4);                    // 16384*256
    bf16*  E_BF  = H_BF + (size_t)N_NODES * 256;        // 4*16384*128
    bf16*  WT    = E_BF + (size_t)HOPS * N_NODES * 128;
    bf16*  W1T   = WT + WT_N;
    bf16*  W2T   = W1T + W1T_N;
    bf16*  WPT   = W2T + W2T_N;
    unsigned char* HK_F8 = (unsigned char*)(WPT + WPT_N);  // 4*16384*256 bytes

    // conversions + tn/l_sep + dtype flag + ACC init (self-detecting blocks)
    cvt_all<<<NB_ALL, 256, 0, stream>>>(
        h, e, Wphi, w1, b1, w2, b2, tphi, W, bias, z, CV,
        WT, W1T, W2T, WPT, H_BF, E_BF, TN, ACC, FLAG);

    // hk (fp8) + phi (f32, folded into hid blocks) + hid->delta: one dispatch
    gemm_all<<<dim3(GA_TOTAL), 256, 0, stream>>>(
        H_BF, E_BF, WT, WPT, W1T, W2T,
        CV + CV_B1, CV + CV_B2, TN, HK_F8, PHI, DELTA, ACC + 1);

    // per-node edge softmax + aggregation + normalize (hop-XCD-affine)
    edge_agg2<<<dim3(N_NODES), 256, 0, stream>>>(
        HK_F8, PHI, DELTA, src, CV + CV_BIAS, OUTS);

    fuse_kernel<<<dim3(N_NODES / 4), 256, 0, stream>>>(
        OUTS, CV + CV_Z, d_out, FLAG, ACC);
}

// Round 6
// 194.804 us; speedup vs baseline: 1.0292x; 1.0292x over previous
//
#include <hip/hip_runtime.h>
#include <hip/hip_bf16.h>

#define N_NODES 16384
#define K_NBR 16
#define HOPS 4
#define IN_DIM 256
#define RAW_DIM 128
#define OUT_DIM 64
#define PHI_DIM 16
#define N_KERN 4
#define E_EDGES (N_NODES * K_NBR)

typedef __hip_bfloat16 bf16;
typedef __attribute__((ext_vector_type(8))) short short8;
typedef __attribute__((ext_vector_type(4))) float f32x4;
typedef __attribute__((ext_vector_type(2))) float f32x2;
typedef __attribute__((ext_vector_type(4))) unsigned int uint4v;

__device__ __forceinline__ float toF(float x) { return x; }
__device__ __forceinline__ float toF(bf16 x) { return __bfloat162float(x); }
__device__ __forceinline__ short f2bfbits(float f)
{
    bf16 b = __float2bfloat16(f);
    short s; __builtin_memcpy(&s, &b, 2); return s;
}

// LDS XOR swizzle (64-short rows): flips short-index bits 3..5 within a row.
// WRITE side is global_load_lds (linear LDS dest) with the same involution
// applied to the global SOURCE chunk index (both-sides-or-neither).
#define SWZ(row, colShort) ((colShort) ^ (((row) & 7) << 3))
// 32-short-row variant (hk BK=32): chunk ^= (row>>1)&3 -> 2-way max (free).
#define SWZ32(row, colShort) ((colShort) ^ ((((row) >> 1) & 3) << 3))

// async 16B global->LDS (linear dest = wave base + lane*16)
__device__ __forceinline__ void gld_lds16(const bf16* g, short* l)
{
    __builtin_amdgcn_global_load_lds(
        (const __attribute__((address_space(1))) unsigned int*)g,
        (__attribute__((address_space(3))) unsigned int*)l, 16, 0, 0);
}

// ds_swizzle xor-reduce step (BitMode: offset = (xor<<10)|0x1F)
template <int IMM>
__device__ __forceinline__ float swzx(float v)
{
    return __builtin_bit_cast(float,
        __builtin_amdgcn_ds_swizzle(__builtin_bit_cast(int, v), IMM));
}
#define XOR1  0x041F
#define XOR2  0x081F
#define XOR4  0x101F
#define XOR8  0x201F
#define XOR16 0x401F

// packed f32 FMA, acc = broadcast(w.word0 or word1) * x + acc (VOP3P op_sel)
__device__ __forceinline__ void pkfma_w0(f32x2& acc, f32x2 w, f32x2 x)
{
    asm("v_pk_fma_f32 %0, %1, %2, %0 op_sel:[0,0,0] op_sel_hi:[0,1,1]"
        : "+v"(acc) : "v"(w), "v"(x));
}
__device__ __forceinline__ void pkfma_w1(f32x2& acc, f32x2 w, f32x2 x)
{
    asm("v_pk_fma_f32 %0, %1, %2, %0 op_sel:[1,0,0] op_sel_hi:[1,1,1]"
        : "+v"(acc) : "v"(w), "v"(x));
}

// ------------------- compact f32 workspace (live values only) --------------
// w1/w2/W/wphi f32 copies were DEAD (only bf16 transposes are consumed).
#define CVC_B1   0
#define CVC_B2   (CVC_B1 + HOPS * IN_DIM)            // 1024
#define CVC_BIAS (CVC_B2 + HOPS * PHI_DIM * N_KERN)  // 1280
#define CVC_Z    (CVC_BIAS + HOPS * OUT_DIM)         // 1536
#define CVC_END  (CVC_Z + OUT_DIM)                   // 1600

// transposed bf16 weight region sizes
#define WT_N  (HOPS * 256 * 256)
#define W1T_N (HOPS * 256 * 128)
#define W2T_N (HOPS * 64 * 256)
#define WPT_N (HOPS * 16 * 128)
#define CVT_TOTAL (WT_N + W1T_N + W2T_N + WPT_N)     // 466944

// cvt_all block ranges (vectorized: WT x4/thread, h/e x8 vec8/thread)
#define NB_CV ((CVC_END + 255) / 256)                // 7
#define NB_WT (CVT_TOTAL / 1024)                     // 456 exact
#define NB_H  (N_NODES * 256 / 8 / 2048)             // 256
#define NB_E  (HOPS * N_NODES * 128 / 8 / 2048)      // 512
#define NB_ALL (NB_CV + NB_WT + NB_H + NB_E + 1)     // 1232

#define GA_TOTAL 2048

__device__ __forceinline__ float loadDyn(const void* p, int i, bool isbf)
{
    return isbf ? toF(((const bf16*)p)[i]) : ((const float*)p)[i];
}

// 8-wide dyn -> bf16 conversion helper
__device__ __forceinline__ void cvt8(bf16* dst, const void* src, size_t base, bool isbf)
{
    short8 v;
    if (isbf) {
        v = *(const short8*)((const bf16*)src + base);
    } else {
        const float* sp = (const float*)src + base;
        f32x4 f0 = *(const f32x4*)sp;
        f32x4 f1 = *(const f32x4*)(sp + 4);
#pragma unroll
        for (int j = 0; j < 4; j++) { v[j] = f2bfbits(f0[j]); v[4 + j] = f2bfbits(f1[j]); }
    }
    *(short8*)(dst + base) = v;
}

// ---------------------------------------------------------------------------
// cvt_all: (a) live small weights -> f32 CV, (b) transposed bf16 weights
// (x4/thread), (c) h -> bf16 (x8 vec8/thread), (d) e -> bf16 (x8),
// (e) tn + l_sep + FLAG/ACC (last block). Self-detects dtype from h.
// ---------------------------------------------------------------------------
__global__ __launch_bounds__(256) void cvt_all(
    const void* h, const void* e,
    const void* wphi, const void* w1, const void* b1, const void* w2,
    const void* b2, const void* tphi, const void* W, const void* bias,
    const void* z, float* __restrict__ CV,
    bf16* __restrict__ wt, bf16* __restrict__ w1t, bf16* __restrict__ w2t,
    bf16* __restrict__ wpt, bf16* __restrict__ h_bf, bf16* __restrict__ e_bf,
    float* __restrict__ tn_out, float* __restrict__ acc, int* __restrict__ flagOut)
{
    __shared__ float s_det[4];
    int tid = threadIdx.x;
    // ---- self-detect ----
    {
        unsigned short pv = ((const unsigned short*)h)[tid];
        unsigned int bits = ((unsigned int)pv) << 16;
        float v; __builtin_memcpy(&v, &bits, 4);
        v = fabsf(v);
        if (!(v == v) || v > 1e30f) v = 1e30f;
#pragma unroll
        for (int off = 32; off > 0; off >>= 1) v = fmaxf(v, __shfl_xor(v, off));
        if ((tid & 63) == 0) s_det[tid >> 6] = v;
    }
    __syncthreads();
    bool isbf = fmaxf(fmaxf(s_det[0], s_det[1]), fmaxf(s_det[2], s_det[3])) < 1e4f;

    int b = blockIdx.x;
    if (b == NB_ALL - 1) {
        // ---- tn = row-normalized tilde_phi (no eps) + l_sep; writes ACC/FLAG ----
        __shared__ float s_v[256], s_tn[256], s_red[256], s_hop[4];
        int hop = tid >> 6, t64 = tid & 63;
        int row = t64 >> 4, p = t64 & 15;
        float v = loadDyn(tphi, hop * 64 + t64, isbf);
        s_v[tid] = v;
        __syncthreads();
        float ss = 0.f;
        for (int q = 0; q < 16; q++) { float x = s_v[hop * 64 + row * 16 + q]; ss += x * x; }
        float tnv = v / sqrtf(ss);
        tn_out[hop * 64 + t64] = tnv;
        s_tn[tid] = tnv;
        __syncthreads();
        float s = 0.f;
        for (int j = 0; j < 4; j++) {
            float d = tnv - s_tn[hop * 64 + j * 16 + p];
            s += d * d;
        }
        s_red[tid] = s;
        __syncthreads();
        if (t64 == 0) {
            float tot = 0.f;
            for (int i = 0; i < 64; i++) tot += s_red[hop * 64 + i];
            s_hop[hop] = tot;
        }
        __syncthreads();
        if (tid == 0) {
            acc[0] = (s_hop[0] + s_hop[1] + s_hop[2] + s_hop[3]) * 0.0625f;
            acc[1] = 0.f;                        // l_focus accumulator
            *flagOut = isbf ? 1 : 0;
        }
        return;
    }
    if (b < NB_CV) {
        int idx = b * 256 + tid;
        if (idx >= CVC_END) return;
        float v;
        if      (idx < CVC_B2)   v = loadDyn(b1,   idx - CVC_B1,   isbf);
        else if (idx < CVC_BIAS) v = loadDyn(b2,   idx - CVC_B2,   isbf);
        else if (idx < CVC_Z)    v = loadDyn(bias, idx - CVC_BIAS, isbf);
        else                     v = loadDyn(z,    idx - CVC_Z,    isbf);
        CV[idx] = v;
        return;
    }
    b -= NB_CV;
    if (b < NB_WT) {
        int base = (b * 256 + tid) * 4;
#pragma unroll
        for (int jj = 0; jj < 4; jj++) {
            int idx = base + jj;
            if (idx < WT_N) {                      // 256N x 256K per hop
                int o = idx, hop = o >> 16, rem = o & 65535, n = rem >> 8, k = rem & 255;
                wt[o] = __float2bfloat16(loadDyn(W, hop * 65536 + k * 256 + n, isbf));
            } else if (idx < WT_N + W1T_N) {       // 256N x 128K per hop
                int o = idx - WT_N, hop = o >> 15, rem = o & 32767, n = rem >> 7, k = rem & 127;
                w1t[o] = __float2bfloat16(loadDyn(w1, hop * 32768 + k * 256 + n, isbf));
            } else if (idx < WT_N + W1T_N + W2T_N) { // 64N x 256K per hop
                int o = idx - WT_N - W1T_N, hop = o >> 14, rem = o & 16383, n = rem >> 8, k = rem & 255;
                w2t[o] = __float2bfloat16(loadDyn(w2, hop * 16384 + k * 64 + n, isbf));
            } else {                               // 16N x 128K per hop (row 15 zero)
                int o = idx - WT_N - W1T_N - W2T_N, hop = o >> 11, rem = o & 2047, n = rem >> 7, k = rem & 127;
                float v = (n < 15) ? loadDyn(wphi, hop * 1920 + k * 15 + n, isbf) : 0.f;
                wpt[o] = __float2bfloat16(v);
            }
        }
        return;
    }
    b -= NB_WT;
    if (b < NB_H) {
#pragma unroll
        for (int k = 0; k < 8; k++) {
            size_t base = ((size_t)b * 2048 + k * 256 + tid) * 8;
            cvt8(h_bf, h, base, isbf);
        }
        return;
    }
    b -= NB_H;
    {
#pragma unroll
        for (int k = 0; k < 8; k++) {
            size_t base = ((size_t)b * 2048 + k * 256 + tid) * 8;
            cvt8(e_bf, e, base, isbf);
        }
    }
}

// ---------------------------------------------------------------------------
// hk GEMM: C = h @ W, 128x128 tile, K=256, BK=32, 2-phase double-buffered.
// LDS: buf b at smem + b*16KB: As[128][32] + Bs[128][32] (linear, source-
// swizzled SWZ32 via gld_lds). One barrier per K-step.
// Output fp8-e4m3 staged through LDS.
// ---------------------------------------------------------------------------
__device__ __forceinline__ void gemm_hk_dev(
    char* smem, const bf16* __restrict__ A, const bf16* __restrict__ Bt,
    unsigned char* __restrict__ Cg, int colBase, int rowBase)
{
    short* base = (short*)smem;
    int tid = threadIdx.x;
    int w = tid >> 6, lane = tid & 63;
    int wr = w >> 1, wc = w & 1;
    int l16 = lane & 15, quad = lane >> 4;
    f32x4 acc[4][4] = {};

#define HK_STAGE(bufb, k0v)                                                          \
    {                                                                                \
        short* As_ = base + (bufb) * 8192;                                           \
        short* Bs_ = As_ + 4096;                                                     \
        for (int id = tid; id < 128 * 4; id += 256) {                                \
            int row = id >> 2, j = id & 3;                                           \
            gld_lds16(A + (size_t)(rowBase + row) * 256 + (k0v) +                    \
                          ((j ^ ((row >> 1) & 3)) * 8),                              \
                      As_ + id * 8);                                                 \
        }                                                                            \
        for (int id = tid; id < 128 * 4; id += 256) {                                \
            int row = id >> 2, j = id & 3;                                           \
            gld_lds16(Bt + (size_t)(colBase + row) * 256 + (k0v) +                   \
                          ((j ^ ((row >> 1) & 3)) * 8),                              \
                      Bs_ + id * 8);                                                 \
        }                                                                            \
    }

    HK_STAGE(0, 0)
    __syncthreads();                       // prologue drain
    for (int t = 0; t < 8; ++t) {
        if (t < 7) HK_STAGE((t + 1) & 1, (t + 1) * 32)   // prefetch next K-slab
        short* As = base + (t & 1) * 8192;
        short* Bs = As + 4096;
        short8 aF[4], bF[4];
#pragma unroll
        for (int mi = 0; mi < 4; mi++) {
            int row = wr * 64 + mi * 16 + l16;
            aF[mi] = *(const short8*)&As[row * 32 + SWZ32(row, quad * 8)];
        }
#pragma unroll
        for (int ni = 0; ni < 4; ni++) {
            int row = wc * 64 + ni * 16 + l16;
            bF[ni] = *(const short8*)&Bs[row * 32 + SWZ32(row, quad * 8)];
        }
#pragma unroll
        for (int mi = 0; mi < 4; mi++)
#pragma unroll
            for (int ni = 0; ni < 4; ni++)
                acc[mi][ni] = __builtin_amdgcn_mfma_f32_16x16x32_bf16(
                    aF[mi], bF[ni], acc[mi][ni], 0, 0, 0);
        __syncthreads();                   // drains prefetch + guards buffer swap
    }
#undef HK_STAGE

    // fp8 epilogue staged in smem [128][128] bytes (buf region, dead now)
    unsigned char* Cs = (unsigned char*)smem;
#pragma unroll
    for (int mi = 0; mi < 4; mi++)
#pragma unroll
        for (int ni = 0; ni < 4; ni++) {
            int cl = wc * 64 + ni * 16 + l16;
#pragma unroll
            for (int r = 0; r < 4; r++) {
                int rl = wr * 64 + mi * 16 + quad * 4 + r;
                float v = acc[mi][ni][r];
                int pk = __builtin_amdgcn_cvt_pk_fp8_f32(v, v, 0, false);
                Cs[rl * 128 + cl] = (unsigned char)(pk & 0xFF);
            }
        }
    __syncthreads();
    for (int c = tid; c < 128 * 8; c += 256) {
        int r = c >> 3, off = (c & 7) * 16;
        *(uint4v*)(Cg + ((size_t)(rowBase + r) * 256 + colBase) + off) =
            *(const uint4v*)(Cs + (size_t)r * 128 + off);
    }
}

// ---------------------------------------------------------------------------
// hid_delta+phi device body: hid = relu(e@w1+b1) (LDS-only) -> delta =
// hid@w2+b2 (+tn, l_focus); phi = e@Wphi folded into phase 1 (wave 0).
// LDS plan (45056 B total, heavy aliasing) as before.
// ---------------------------------------------------------------------------
__device__ __forceinline__ void hid_delta_dev(
    char* smem,
    const bf16* __restrict__ A, const bf16* __restrict__ B1,
    const bf16* __restrict__ B2, const bf16* __restrict__ WP,
    const float* __restrict__ b1, const float* __restrict__ b2,
    const float* __restrict__ tn, float* __restrict__ Dg,
    float* __restrict__ phiG, float* __restrict__ lfocus, int rowBase)
{
    short* As  = (short*)smem;           // [64][64] phase 1
    short* Bs  = As + 64 * 64;           // [256][64] phase 1
    short* Wpa = As + 20480;             // [16][128] full-K Wphi^T
    short* Hs  = (short*)smem;           // [64][256] phase 2 (aliases As/Bs)
    short* B2s = Hs + 64 * 256;          // [64][64] phase 2 quarter buffer
    float* Ds  = (float*)smem;           // [64][64] f32 epilogue
    float* s_w = (float*)(smem + 40944); // tail of B2s

    int tid = threadIdx.x;
    int w = tid >> 6, lane = tid & 63;
    int l16 = lane & 15, quad = lane >> 4;

    // ---- phase 1: hid = relu(e @ w1 + b1) -> Hs ; phi (wave 0) ----
    {
        f32x4 acc[4][4] = {};
        f32x4 accp[4] = {};
        for (int k0 = 0; k0 < 128; k0 += 64) {
            for (int id = tid; id < 64 * 8; id += 256) {
                int row = id >> 3, j = id & 7;
                gld_lds16(A + (size_t)(rowBase + row) * 128 + k0 + ((j ^ (row & 7)) * 8),
                          As + id * 8);
            }
            for (int id = tid; id < 256 * 8; id += 256) {
                int row = id >> 3, j = id & 7;
                gld_lds16(B1 + (size_t)row * 128 + k0 + ((j ^ (row & 7)) * 8),
                          Bs + id * 8);
            }
            if (k0 == 0) {                 // Wphi^T: 16 rows x 16 chunks, full K
                int row = tid >> 4, j = tid & 15;
                gld_lds16(WP + (size_t)row * 128 + ((j ^ (row & 7)) * 8),
                          Wpa + tid * 8);
            }
            __syncthreads();
#pragma unroll
            for (int kc = 0; kc < 64; kc += 32) {
                short8 aF[4], bF[4];
#pragma unroll
                for (int mi = 0; mi < 4; mi++) {
                    int row = mi * 16 + l16;
                    aF[mi] = *(const short8*)&As[row * 64 + SWZ(row, kc + quad * 8)];
                }
#pragma unroll
                for (int ni = 0; ni < 4; ni++) {
                    int row = w * 64 + ni * 16 + l16;
                    bF[ni] = *(const short8*)&Bs[row * 64 + SWZ(row, kc + quad * 8)];
                }
#pragma unroll
                for (int mi = 0; mi < 4; mi++)
#pragma unroll
                    for (int ni = 0; ni < 4; ni++)
                        acc[mi][ni] = __builtin_amdgcn_mfma_f32_16x16x32_bf16(
                            aF[mi], bF[ni], acc[mi][ni], 0, 0, 0);
                if (w == 0) {
                    short8 bFp = *(const short8*)&Wpa[l16 * 128 + SWZ(l16, k0 + kc + quad * 8)];
#pragma unroll
                    for (int mi = 0; mi < 4; mi++)
                        accp[mi] = __builtin_amdgcn_mfma_f32_16x16x32_bf16(
                            aF[mi], bFp, accp[mi], 0, 0, 0);
                }
            }
            __syncthreads();
        }
        // epilogue -> Hs (As/Bs dead); stage B2 quarter 0; write phi (wave 0)
#pragma unroll
        for (int mi = 0; mi < 4; mi++) {
#pragma unroll
            for (int ni = 0; ni < 4; ni++) {
                int col = w * 64 + ni * 16 + l16;
                float bv = b1[col];
#pragma unroll
                for (int r = 0; r < 4; r++) {
                    int row = mi * 16 + quad * 4 + r;
                    float v = fmaxf(acc[mi][ni][r] + bv, 0.f);
                    Hs[row * 256 + SWZ(row, col)] = f2bfbits(v);
                }
            }
        }
        for (int id = tid; id < 64 * 8; id += 256) {     // B2 quarter 0
            int row = id >> 3, j = id & 7;
            gld_lds16(B2 + (size_t)row * 256 + ((j ^ (row & 7)) * 8),
                      B2s + id * 8);
        }
        if (w == 0) {
#pragma unroll
            for (int mi = 0; mi < 4; mi++)
#pragma unroll
                for (int r = 0; r < 4; r++)
                    phiG[(size_t)(rowBase + mi * 16 + quad * 4 + r) * 16 + l16] =
                        accp[mi][r];
        }
    }

    // ---- phase 2: delta = Hs @ w2 + b2 (w2 staged in K=64 quarters) ----
    {
        f32x4 acc2[4] = {};
        for (int q = 0; q < 4; q++) {
            __syncthreads();   // q=0: Hs+B2s0 writes done; q>0: prev reads done
#pragma unroll
            for (int kcq = 0; kcq < 64; kcq += 32) {
                int arow = w * 16 + l16;
                short8 aF = *(const short8*)&Hs[arow * 256 + SWZ(arow, q * 64 + kcq + quad * 8)];
                short8 bF[4];
#pragma unroll
                for (int ni = 0; ni < 4; ni++) {
                    int row = ni * 16 + l16;
                    bF[ni] = *(const short8*)&B2s[row * 64 + SWZ(row, kcq + quad * 8)];
                }
#pragma unroll
                for (int ni = 0; ni < 4; ni++)
                    acc2[ni] = __builtin_amdgcn_mfma_f32_16x16x32_bf16(aF, bF[ni], acc2[ni], 0, 0, 0);
            }
            if (q < 3) {
                __syncthreads();                         // all reads of quarter q done
                for (int id = tid; id < 64 * 8; id += 256) {
                    int row = id >> 3, j = id & 7;
                    gld_lds16(B2 + (size_t)row * 256 + (q + 1) * 64 + ((j ^ (row & 7)) * 8),
                              B2s + id * 8);
                }
            }
        }
        __syncthreads();   // all MFMA reads done before Ds/s_w overwrite LDS
        float sq = 0.f;
#pragma unroll
        for (int ni = 0; ni < 4; ni++) {
            int col = ni * 16 + l16;
            float bv = b2[col], tv = tn[col];
#pragma unroll
            for (int r = 0; r < 4; r++) {
                int row = w * 16 + quad * 4 + r;
                float v = acc2[ni][r] + bv;
                sq += v * v;
                Ds[row * 64 + col] = v + tv;
            }
        }
#pragma unroll
        for (int off = 32; off > 0; off >>= 1) sq += __shfl_xor(sq, off);
        if (lane == 0) s_w[w] = sq;
        __syncthreads();
        for (int c = tid; c < 64 * 16; c += 256) {       // 16 x 16B chunks/row
            int r = c >> 4, off = (c & 15) * 4;
            *(uint4v*)(Dg + (size_t)(rowBase + r) * 64 + off) =
                *(const uint4v*)(Ds + (size_t)r * 64 + off);
        }
        if (tid == 0) atomicAdd(lfocus, s_w[0] + s_w[1] + s_w[2] + s_w[3]);
    }
}

// ---------------------------------------------------------------------------
// gemm_all: XCD-affine mapping for L2 reuse (XCD = blockIdx % 8):
//  - XCD x, position p = b>>3 (0..255); even p -> hk, odd p -> hid (type mix).
//  - hk slot s = p>>1: row-group rg = x*16 + (s>>3) with ALL 8 (hop,part)
//    variants adjacent on the same XCD -> A-tile L2-hits 7/8 (67 -> 8 MB L3).
//  - hid slot s: hop = x&3, tile = (x>=4)*128 + s -> B1/B2/WPT L2-resident.
// smem = 45056 B.
// ---------------------------------------------------------------------------
__global__ __launch_bounds__(256) void gemm_all(
    const bf16* __restrict__ h_bf, const bf16* __restrict__ e_bf,
    const bf16* __restrict__ WT, const bf16* __restrict__ WPT,
    const bf16* __restrict__ W1T, const bf16* __restrict__ W2T,
    const float* __restrict__ b1All, const float* __restrict__ b2All,
    const float* __restrict__ tnAll, unsigned char* __restrict__ hk_f8,
    float* __restrict__ phi, float* __restrict__ DELTA, float* __restrict__ lfocus)
{
    __shared__ __align__(16) char smem[45056];
    int b = blockIdx.x;
    int x = b & 7;
    int p = b >> 3;
    int s = p >> 1;
    if ((p & 1) == 0) {
        int rg = x * 16 + (s >> 3);
        int v = s & 7;
        int hop = v >> 1, part = v & 1;
        gemm_hk_dev(smem, h_bf, WT + (size_t)hop * 65536,
                    hk_f8 + (size_t)hop * N_NODES * 256, part * 128, rg * 128);
    } else {
        int hop = x & 3;
        int tile = ((x >> 2) << 7) + s;
        hid_delta_dev(smem,
            e_bf + (size_t)hop * N_NODES * 128,
            W1T + (size_t)hop * 32768, W2T + (size_t)hop * 16384,
            WPT + (size_t)hop * 2048,
            b1All + hop * 256, b2All + hop * 64, tnAll + hop * 64,
            DELTA + (size_t)hop * N_NODES * 64,
            phi + (size_t)hop * N_NODES * 16, lfocus, tile * 64);
    }
}

// ---------------------------------------------------------------------------
// edge_agg2: wave-synchronous, 4 nodes (one hop) per 256-thread block.
// hop = blockIdx.x & 3 (XCD affinity). VALU-diet version.
// ---------------------------------------------------------------------------
__global__ __launch_bounds__(256) void edge_agg2(
    const unsigned char* __restrict__ hk, const float* __restrict__ phi,
    const float* __restrict__ dik, const int* __restrict__ src,
    const float* __restrict__ biasAll, float* __restrict__ outs)
{
    int b = blockIdx.x;
    int hop = b & 3;                 // XCD affinity: hop h -> XCDs {h, h+4}
    int wave = threadIdx.x >> 6, lane = threadIdx.x & 63;
    int node = (b >> 2) * 4 + wave;
    const unsigned char* hk_l = hk + (size_t)hop * N_NODES * 256;
    const float* phi_l  = phi + (size_t)hop * N_NODES * 16;
    const float* dik_l  = dik + (size_t)hop * N_NODES * 64;
    const int*   src_n  = src + (size_t)hop * E_EDGES + (size_t)node * 16;
    const float* bias_l = biasAll + hop * 64;
    float*       outs_n = outs + ((size_t)hop * N_NODES + node) * 64;

    __shared__ __align__(16) float s_dik[4][64];
    __shared__ __align__(16) float s_attT[4][4][24];  // [wave][k][edge]
    __shared__ int   s_src[4][16];

    s_dik[wave][lane] = dik_l[(size_t)node * 64 + lane];
    if (lane < 16) s_src[wave][lane] = src_n[lane];

    // ---- stage 1: dist + logits (4 lanes per edge; lane = 4e + q) ----
    int e = lane >> 2, q = lane & 3;
    int sN = s_src[wave][e];
    f32x4 ps = *(const f32x4*)(phi_l + (size_t)sN * 16 + q * 4);
    f32x4 pd = *(const f32x4*)(phi_l + (size_t)node * 16 + q * 4);
    float d0 = ps[0] - pd[0], d1 = ps[1] - pd[1];
    float d2 = ps[2] - pd[2], d3 = ps[3] - pd[3];
    bool q3 = (q == 3);            // p15 = flag col (phi col15 == 0)
    float ssp = d0 * d0 + d1 * d1 + d2 * d2 + (q3 ? 0.f : d3 * d3);
    ssp += swzx<XOR1>(ssp); ssp += swzx<XOR2>(ssp);
    float last = (ssp == 0.f) ? 1.f : 0.f;   // all dist==0 <=> ssp==0
    if (q3) d3 = last;
    float inv = fminf(__builtin_amdgcn_rsqf(ssp + last * last), 1e8f);
#pragma unroll
    for (int k = 0; k < 4; k++) {
        f32x4 dkv = *(const f32x4*)&s_dik[wave][k * 16 + q * 4];
        float pk = d0 * dkv[0] + d1 * dkv[1] + d2 * dkv[2] + d3 * dkv[3];
        pk += swzx<XOR1>(pk); pk += swzx<XOR2>(pk);
        if (q == k) s_attT[wave][k][e] = pk * inv;
    }

    // ---- stage 2: softmax over 16 edges per k (lane = 4e + k) ----
    int k2 = lane & 3;
    float lgv = s_attT[wave][k2][e];
    float mx = lgv;
    mx = fmaxf(mx, swzx<XOR4>(mx));
    mx = fmaxf(mx, swzx<XOR8>(mx));
    mx = fmaxf(mx, swzx<XOR16>(mx));
    mx = fmaxf(mx, __shfl_xor(mx, 32));
    float ex = __expf(lgv - mx);
    float den = ex;
    den += swzx<XOR4>(den);
    den += swzx<XOR8>(den);
    den += swzx<XOR16>(den);
    den += __shfl_xor(den, 32);
    s_attT[wave][k2][e] = ex * __builtin_amdgcn_rcpf(den);

    // ---- stage 3: aggregation (lane = kk*16 + dim-group; 4 dims/lane) ----
    int kk = lane >> 4, dsub = (lane & 15) * 4;
    f32x2 att2[8];
#pragma unroll
    for (int g = 0; g < 8; g++) att2[g] = *(const f32x2*)&s_attT[wave][kk][g * 2];
    f32x2 a01 = {0.f, 0.f}, a23 = {0.f, 0.f};
#pragma unroll
    for (int ep = 0; ep < 8; ep++) {
        int sm0 = __builtin_amdgcn_readfirstlane(s_src[wave][2 * ep]);
        int sm1 = __builtin_amdgcn_readfirstlane(s_src[wave][2 * ep + 1]);
        unsigned int u0 = *(const unsigned int*)(hk_l + (size_t)sm0 * 256 + lane * 4);
        unsigned int u1 = *(const unsigned int*)(hk_l + (size_t)sm1 * 256 + lane * 4);
        f32x2 w = att2[ep];
        pkfma_w0(a01, w, __builtin_amdgcn_cvt_pk_f32_fp8((int)u0, false));
        pkfma_w0(a23, w, __builtin_amdgcn_cvt_pk_f32_fp8((int)u0, true));
        pkfma_w1(a01, w, __builtin_amdgcn_cvt_pk_f32_fp8((int)u1, false));
        pkfma_w1(a23, w, __builtin_amdgcn_cvt_pk_f32_fp8((int)u1, true));
    }
    float a0 = a01[0], a1 = a01[1], a2 = a23[0], a3 = a23[1];
    a0 += swzx<XOR16>(a0); a0 += __shfl_xor(a0, 32);
    a1 += swzx<XOR16>(a1); a1 += __shfl_xor(a1, 32);
    a2 += swzx<XOR16>(a2); a2 += __shfl_xor(a2, 32);
    a3 += swzx<XOR16>(a3); a3 += __shfl_xor(a3, 32);
    f32x4 bv = *(const f32x4*)(bias_l + dsub);
    float o0 = a0 + bv[0];
    float o1 = a1 + bv[1];
    float o2 = a2 + bv[2];
    float o3 = a3 + bv[3];
    float ssq = o0 * o0 + o1 * o1 + o2 * o2 + o3 * o3;
    ssq += swzx<XOR1>(ssq);
    ssq += swzx<XOR2>(ssq);
    ssq += swzx<XOR4>(ssq);
    ssq += swzx<XOR8>(ssq);
    float inv2 = fminf(__builtin_amdgcn_rsqf(ssq), 1e8f);
    if (kk == 0) {
        f32x4 st;
        st[0] = o0 * inv2; st[1] = o1 * inv2; st[2] = o2 * inv2; st[3] = o3 * inv2;
        *(f32x4*)(outs_n + dsub) = st;
    }
}

// Hop fusion + output store (dtype by flag) + scalar outputs (block 0).
__global__ __launch_bounds__(256) void fuse_kernel(
    const float* __restrict__ outs, const float* __restrict__ z,
    void* __restrict__ out, const int* __restrict__ flag,
    const float* __restrict__ acc)
{
    int tid = threadIdx.x;
    int node = blockIdx.x * 4 + (tid >> 6);
    int dd = tid & 63;
    float zv = z[dd];
    float o[4], sc[4];
#pragma unroll
    for (int h = 0; h < 4; h++) {
        o[h] = outs[((size_t)h * N_NODES + node) * 64 + dd];
        float v = o[h] * zv;
#pragma unroll
        for (int off = 32; off > 0; off >>= 1) v += __shfl_xor(v, off);
        sc[h] = v;
    }
    float mx = fmaxf(fmaxf(sc[0], sc[1]), fmaxf(sc[2], sc[3]));
    float e0 = __expf(sc[0] - mx), e1 = __expf(sc[1] - mx);
    float e2 = __expf(sc[2] - mx), e3 = __expf(sc[3] - mx);
    float den = e0 + e1 + e2 + e3;
    float t = (e0 * o[0] + e1 * o[1] + e2 * o[2] + e3 * o[3]) * __builtin_amdgcn_rcpf(den);
    size_t oi = (size_t)node * 64 + dd;
    bool isbf = (*flag != 0);
    if (isbf) ((bf16*)out)[oi] = __float2bfloat16(t);
    else      ((float*)out)[oi] = t;
    if (blockIdx.x == 0 && tid == 0) {
        float a = acc[0];                                 // l_sep (already scaled)
        float b = acc[1] / ((float)N_NODES * 4.f * 4.f);  // l_focus mean
        size_t base = (size_t)N_NODES * 64;
        if (isbf) {
            ((bf16*)out)[base]     = __float2bfloat16(a);
            ((bf16*)out)[base + 1] = __float2bfloat16(b);
        } else {
            ((float*)out)[base]     = a;
            ((float*)out)[base + 1] = b;
        }
    }
}

extern "C" void kernel_launch(void* const* d_in, const int* in_sizes, int n_in,
                              void* d_out, int out_size, void* d_ws, size_t ws_size,
                              hipStream_t stream)
{
    const void* h    = d_in[0];
    const void* e    = d_in[1];
    const int*  src  = (const int*)d_in[2];
    const void* Wphi = d_in[4];
    const void* w1   = d_in[5];
    const void* b1   = d_in[6];
    const void* w2   = d_in[7];
    const void* b2   = d_in[8];
    const void* tphi = d_in[9];
    const void* W    = d_in[10];
    const void* bias = d_in[11];
    const void* z    = d_in[12];

    float* ws    = (float*)d_ws;
    float* CV    = ws;                                  // CVC_END
    float* OUTS  = CV + CVC_END;                        // 4*16384*64
    float* PHI   = OUTS + (size_t)4 * N_NODES * 64;     // 4*16384*16
    float* DELTA = PHI + (size_t)4 * N_NODES * 16;      // 4*16384*64
    float* TN    = DELTA + (size_t)4 * N_NODES * 64;    // 4*64
    float* ACC   = TN + 256;                            // 2 (+pad)
    int*   FLAG  = (int*)(ACC + 2);
    bf16*  H_BF  = (bf16*)(ACC + 4);                    // 16384*256
    bf16*  E_BF  = H_BF + (size_t)N_NODES * 256;        // 4*16384*128
    bf16*  WT    = E_BF + (size_t)HOPS * N_NODES * 128;
    bf16*  W1T   = WT + WT_N;
    bf16*  W2T   = W1T + W1T_N;
    bf16*  WPT   = W2T + W2T_N;
    unsigned char* HK_F8 = (unsigned char*)(WPT + WPT_N);  // 4*16384*256 bytes

    // conversions + tn/l_sep + dtype flag + ACC init (self-detecting blocks)
    cvt_all<<<NB_ALL, 256, 0, stream>>>(
        h, e, Wphi, w1, b1, w2, b2, tphi, W, bias, z, CV,
        WT, W1T, W2T, WPT, H_BF, E_BF, TN, ACC, FLAG);

    // hk (fp8) + phi (f32, folded into hid blocks) + hid->delta: one dispatch
    gemm_all<<<dim3(GA_TOTAL), 256, 0, stream>>>(
        H_BF, E_BF, WT, WPT, W1T, W2T,
        CV + CVC_B1, CV + CVC_B2, TN, HK_F8, PHI, DELTA, ACC + 1);

    // per-node edge softmax + aggregation + normalize (hop-XCD-affine)
    edge_agg2<<<dim3(N_NODES), 256, 0, stream>>>(
        HK_F8, PHI, DELTA, src, CV + CVC_BIAS, OUTS);

    fuse_kernel<<<dim3(N_NODES / 4), 256, 0, stream>>>(
        OUTS, CV + CVC_Z, d_out, FLAG, ACC);
}